// Round 5
// baseline (303.220 us; speedup 1.0000x reference)
//
#include <hip/hip_runtime.h>
#include <hip/hip_fp16.h>
#include <math.h>

typedef unsigned short u16;
typedef _Float16 f16x8 __attribute__((ext_vector_type(8)));
typedef float f32x4 __attribute__((ext_vector_type(4)));

#define LOG2E 1.4426950408889634f

static __device__ __forceinline__ u16 f2h(float f) {
    _Float16 h = (_Float16)f;
    return __builtin_bit_cast(u16, h);
}
// raw v_sqrt/v_exp/v_rcp (~1ULP) — avoid IEEE guarded expansions
static __device__ __forceinline__ float fsqrt_raw(float x) {
    float r; asm("v_sqrt_f32 %0, %1" : "=v"(r) : "v"(x)); return r;
}
static __device__ __forceinline__ float fexp2_raw(float x) {
    float r; asm("v_exp_f32 %0, %1" : "=v"(r) : "v"(x)); return r;
}
static __device__ __forceinline__ float frcp_raw(float x) {
    float r; asm("v_rcp_f32 %0, %1" : "=v"(r) : "v"(x)); return r;
}

// ---------------- fused prep: x->f16+sq | weight-norm | spa table ----------------
__global__ __launch_bounds__(256) void prep_all(
    const float* __restrict__ x, u16* __restrict__ xh, float* __restrict__ sq,
    const float* __restrict__ vq, const float* __restrict__ gq,
    const float* __restrict__ v1, const float* __restrict__ g1,
    const float* __restrict__ v2, const float* __restrict__ g2,
    u16* __restrict__ wq, u16* __restrict__ w1, u16* __restrict__ w2,
    float* __restrict__ tab, float c2) {
    int bid = blockIdx.x, tid = threadIdx.x;
    int wave = tid >> 6, lane = tid & 63;
    if (bid < 2048) {
        // prep_x: 8192 rows, 4 rows/block
        int row = bid * 4 + wave;
        const float2 v = *reinterpret_cast<const float2*>(x + (size_t)row * 128 + lane * 2);
        float ss = v.x * v.x + v.y * v.y;
#pragma unroll
        for (int m = 1; m < 64; m <<= 1) ss += __shfl_xor(ss, m, 64);
        unsigned int packed = (unsigned int)f2h(v.x) | ((unsigned int)f2h(v.y) << 16);
        *reinterpret_cast<unsigned int*>(xh + (size_t)row * 128 + lane * 2) = packed;
        if (lane == 0) sq[row] = ss;
    } else if (bid < 2208) {
        // prep_w: 640 rows, 4 rows/block
        int row = (bid - 2048) * 4 + wave;
        const float* src; float gv; u16* dst; int r;
        if (row < 384)      { r = row;       src = vq + (size_t)r * 128; gv = gq[r]; dst = wq + (size_t)r * 128; }
        else if (row < 512) { r = row - 384; src = v1 + (size_t)r * 128; gv = g1[r]; dst = w1 + (size_t)r * 128; }
        else                { r = row - 512; src = v2 + (size_t)r * 128; gv = g2[r]; dst = w2 + (size_t)r * 128; }
        float2 v = *reinterpret_cast<const float2*>(src + lane * 2);
        float ss = v.x * v.x + v.y * v.y;
#pragma unroll
        for (int m = 1; m < 64; m <<= 1) ss += __shfl_xor(ss, m, 64);
        float sc = gv / sqrtf(ss);
        unsigned int packed = (unsigned int)f2h(v.x * sc) | ((unsigned int)f2h(v.y * sc) << 16);
        *reinterpret_cast<unsigned int*>(dst + lane * 2) = packed;
    } else {
        // spa table: tab[dx+63][iy][jy] = LOG2E*exp(-dist*c2), 127*4096 entries
        int id = (bid - 2208) * 256 + tid;
        int dxi = id >> 12, rem = id & 4095;
        int iy = rem >> 6, jy = rem & 63;
        float dx = (float)(dxi - 63), dy = (float)(iy - jy);
        float d = fsqrt_raw(fmaf(dx, dx, dy * dy));
        tab[id] = LOG2E * fexp2_raw(-d * c2 * LOG2E);
    }
}

// ---------------- sigma_spe: symmetric — only ti<=tj tiles, off-diag weighted 2x ----------------
__global__ __launch_bounds__(256) void sigma_gemm(const u16* __restrict__ xh,
                                                  const float* __restrict__ sq,
                                                  float* __restrict__ partial) {
    __shared__ u16 xi[128][136];
    __shared__ u16 xj[128][136];
    int bid = blockIdx.x;                 // [0, 1056)
    int b = bid >= 528;
    int idx = bid - b * 528;
    int ti = 0;
    while (idx >= 32 - ti) { idx -= 32 - ti; ++ti; }
    int tj = ti + idx;
    int i0 = ti * 128, j0 = tj * 128;
    float wgt = (ti == tj) ? 1.f : 2.f;
    int tid = threadIdx.x;
    const u16* xsrc = xh + (size_t)b * 4096 * 128;
    for (int t = tid; t < 2048; t += 256) {
        int row = t >> 4, c = (t & 15) * 8;
        *reinterpret_cast<uint4*>(&xi[row][c]) =
            *reinterpret_cast<const uint4*>(xsrc + (size_t)(i0 + row) * 128 + c);
    }
    for (int t = tid; t < 2048; t += 256) {
        int row = t >> 4, c = (t & 15) * 8;
        *reinterpret_cast<uint4*>(&xj[row][c]) =
            *reinterpret_cast<const uint4*>(xsrc + (size_t)(j0 + row) * 128 + c);
    }
    __syncthreads();
    int wave = tid >> 6, lane = tid & 63, lr = lane & 15, lg = lane >> 4;
    f16x8 ai[2][4];
#pragma unroll
    for (int m2 = 0; m2 < 2; ++m2)
#pragma unroll
        for (int ks = 0; ks < 4; ++ks)
            ai[m2][ks] = *reinterpret_cast<const f16x8*>(&xi[wave * 32 + m2 * 16 + lr][ks * 32 + lg * 8]);
    const float* sqb = sq + (size_t)b * 4096;
    float sqi[2][4];
#pragma unroll
    for (int m2 = 0; m2 < 2; ++m2)
#pragma unroll
        for (int r = 0; r < 4; ++r)
            sqi[m2][r] = sqb[i0 + wave * 32 + m2 * 16 + lg * 4 + r];
    float lsum = 0.f;
#pragma unroll
    for (int c = 0; c < 8; ++c) {
        f16x8 bj[4];
#pragma unroll
        for (int ks = 0; ks < 4; ++ks)
            bj[ks] = *reinterpret_cast<const f16x8*>(&xj[c * 16 + lr][ks * 32 + lg * 8]);
        float sqj = sqb[j0 + c * 16 + lr];
#pragma unroll
        for (int m2 = 0; m2 < 2; ++m2) {
            f32x4 acc = {0.f, 0.f, 0.f, 0.f};
#pragma unroll
            for (int ks = 0; ks < 4; ++ks)
                acc = __builtin_amdgcn_mfma_f32_16x16x32_f16(ai[m2][ks], bj[ks], acc, 0, 0, 0);
#pragma unroll
            for (int r = 0; r < 4; ++r) {
                float d2 = fmaf(-2.f, acc[r], sqi[m2][r] + sqj);
                lsum += fsqrt_raw(fmaxf(d2, 0.f));
            }
        }
    }
#pragma unroll
    for (int m = 1; m < 64; m <<= 1) lsum += __shfl_xor(lsum, m, 64);
    if (lane == 0) atomicAdd(&partial[bid], lsum * wgt);
}

__global__ __launch_bounds__(256) void sigma_fin(const float* __restrict__ partial,
                                                 float* __restrict__ accum) {
    __shared__ float red[4];
    float s = 0.f;
    for (int i = threadIdx.x; i < 1056; i += 256) s += partial[i];
#pragma unroll
    for (int m = 1; m < 64; m <<= 1) s += __shfl_xor(s, m, 64);
    int w = threadIdx.x >> 6;
    if ((threadIdx.x & 63) == 0) red[w] = s;
    __syncthreads();
    if (threadIdx.x == 0) {
        float sigma = (red[0] + red[1] + red[2] + red[3]) / 33554432.f;  // 2*4096*4096
        accum[1] = -LOG2E / (2.f * sigma * sigma);  // -c1*log2(e)
    }
}

// ---------------- qkv projection: q pre-scaled by 1/8 ----------------
__global__ __launch_bounds__(256) void qkv_gemm(const u16* __restrict__ xh, const u16* __restrict__ wq,
                                                const float* __restrict__ bq,
                                                u16* __restrict__ q_ws, u16* __restrict__ k_ws,
                                                u16* __restrict__ vt_ws) {
    int cg = blockIdx.x & 1;
    int tok0 = (blockIdx.x >> 1) * 64 + (threadIdx.x >> 6) * 16;
    int lane = threadIdx.x & 63, lr = lane & 15, lg = lane >> 4;
    f16x8 a[4];
#pragma unroll
    for (int ks = 0; ks < 4; ++ks)
        a[ks] = *reinterpret_cast<const f16x8*>(xh + (size_t)(tok0 + lr) * 128 + ks * 32 + lg * 8);
#pragma unroll
    for (int ci = 0; ci < 12; ++ci) {
        int c = cg * 12 + ci;
        f32x4 acc = {0.f, 0.f, 0.f, 0.f};
#pragma unroll
        for (int ks = 0; ks < 4; ++ks) {
            f16x8 bw = *reinterpret_cast<const f16x8*>(wq + (size_t)(c * 16 + lr) * 128 + ks * 32 + lg * 8);
            acc = __builtin_amdgcn_mfma_f32_16x16x32_f16(a[ks], bw, acc, 0, 0, 0);
        }
        int j = c * 16 + lr;
        float bias = bq[j];
        float sc = (j < 128) ? 0.125f : 1.0f;
#pragma unroll
        for (int r = 0; r < 4; ++r) {
            int tokg = tok0 + lg * 4 + r;
            int b = tokg >> 12, n = tokg & 4095;
            u16 hv = f2h((acc[r] + bias) * sc);
            if (j < 128) {
                q_ws[((size_t)(b * 2 + (j >> 6)) * 4096 + n) * 64 + (j & 63)] = hv;
            } else if (j < 256) {
                int jj = j - 128;
                k_ws[((size_t)(b * 2 + (jj >> 6)) * 4096 + n) * 64 + (jj & 63)] = hv;
            } else {
                int jj = j - 256;
                vt_ws[((size_t)(b * 2 + (jj >> 6)) * 64 + (jj & 63)) * 4096 + n] = hv;
            }
        }
    }
}

// ---------------- fused masked attention: prefetched 32-key tiles, split 8 ----------------
__global__ __launch_bounds__(256, 4) void attn_fused(
    const u16* __restrict__ xh, const float* __restrict__ sq,
    const u16* __restrict__ q_ws, const u16* __restrict__ k_ws, const u16* __restrict__ vt_ws,
    const float* __restrict__ accum, const float* __restrict__ spa,
    u16* __restrict__ opart, float* __restrict__ l_ws) {
    __shared__ u16 k_lds[2][32][72];     // 9216 B
    __shared__ u16 vt_lds[2][64][40];    // 10240 B
    __shared__ u16 xk_lds[32][136];      // 8704 B
    __shared__ u16 p_lds[4][2][16][40];  // 10240 B
    __shared__ float sq_lds[32];         // 128 B  (38528 B -> 4 blocks/CU)

    const float nc1L = accum[1];
    const float NEG8L = -8.0f * LOG2E;
    int idx = blockIdx.x;                        // 1024 blocks
    int qt = idx & 63, split = (idx >> 6) & 7, b = idx >> 9;
    int tid = threadIdx.x;
    int w = tid >> 6, lane = tid & 63, lr = lane & 15, lg = lane >> 4;
    int q0 = qt * 64 + w * 16;

    f16x8 aq[2][2], axq[4];
#pragma unroll
    for (int h = 0; h < 2; ++h)
#pragma unroll
        for (int ks = 0; ks < 2; ++ks)
            aq[h][ks] = *reinterpret_cast<const f16x8*>(
                q_ws + ((size_t)(b * 2 + h) * 4096 + q0 + lr) * 64 + ks * 32 + lg * 8);
#pragma unroll
    for (int ks = 0; ks < 4; ++ks)
        axq[ks] = *reinterpret_cast<const f16x8*>(
            xh + ((size_t)b * 4096 + q0 + lr) * 128 + ks * 32 + lg * 8);

    float sqi[4];
    int rowoff[4];
#pragma unroll
    for (int r = 0; r < 4; ++r) {
        sqi[r] = sq[(size_t)b * 4096 + q0 + lg * 4 + r];
        rowoff[r] = (w * 16 + lg * 4 + r) * 64 + lr;
    }

    const f32x4 zero4 = {0.f, 0.f, 0.f, 0.f};
    f32x4 O[2][4];
    float lsum[2][4];
#pragma unroll
    for (int h = 0; h < 2; ++h)
#pragma unroll
        for (int vd = 0; vd < 4; ++vd) O[h][vd] = zero4;
#pragma unroll
    for (int h = 0; h < 2; ++h)
#pragma unroll
        for (int r = 0; r < 4; ++r) lsum[h][r] = 0.f;

    // T14 async-STAGE: per-tile regs loaded one tile ahead
    uint4 rk[2], rv[2], rx[2];
    float rsq = 0.f;
    auto issue_loads = [&](int kb) {
#pragma unroll
        for (int it = 0; it < 2; ++it) {
            int i2 = tid + it * 256;
            { int h2 = i2 >> 8, rem = i2 & 255, row = rem >> 3, c8 = rem & 7;
              rk[it] = *reinterpret_cast<const uint4*>(
                  k_ws + ((size_t)(b * 2 + h2) * 4096 + kb + row) * 64 + c8 * 8); }
            { int h2 = i2 >> 8, rem = i2 & 255, row = rem >> 2, c4 = rem & 3;
              rv[it] = *reinterpret_cast<const uint4*>(
                  vt_ws + ((size_t)(b * 2 + h2) * 64 + row) * 4096 + kb + c4 * 8); }
            { int row = i2 >> 4, c16 = i2 & 15;
              rx[it] = *reinterpret_cast<const uint4*>(
                  xh + ((size_t)b * 4096 + kb + row) * 128 + c16 * 8); }
        }
        if (tid < 32) rsq = sq[(size_t)b * 4096 + kb + tid];
    };
    auto write_lds = [&]() {
#pragma unroll
        for (int it = 0; it < 2; ++it) {
            int i2 = tid + it * 256;
            { int h2 = i2 >> 8, rem = i2 & 255, row = rem >> 3, c8 = rem & 7;
              *reinterpret_cast<uint4*>(&k_lds[h2][row][c8 * 8]) = rk[it]; }
            { int h2 = i2 >> 8, rem = i2 & 255, row = rem >> 2, c4 = rem & 3;
              *reinterpret_cast<uint4*>(&vt_lds[h2][row][c4 * 8]) = rv[it]; }
            { int row = i2 >> 4, c16 = i2 & 15;
              *reinterpret_cast<uint4*>(&xk_lds[row][c16 * 8]) = rx[it]; }
        }
        if (tid < 32) sq_lds[tid] = rsq;
    };

    issue_loads(split * 512);
    for (int t = 0; t < 16; ++t) {
        int kb = split * 512 + t * 32;
        __syncthreads();                 // LDS free (previous compute done)
        write_lds();                     // vmcnt wait folded here by compiler
        __syncthreads();                 // LDS visible
        if (t < 15) issue_loads(kb + 32);  // overlap next tile's loads with compute

        int dxi = qt - (kb >> 6) + 63;
        const float* spa_t = spa + (size_t)dxi * 4096 + (kb & 63);
#pragma unroll
        for (int c = 0; c < 2; ++c) {
            f32x4 Dacc = zero4, S0 = zero4, S1 = zero4;
#pragma unroll
            for (int ks = 0; ks < 4; ++ks) {
                f16x8 bx = *reinterpret_cast<const f16x8*>(&xk_lds[c * 16 + lr][ks * 32 + lg * 8]);
                Dacc = __builtin_amdgcn_mfma_f32_16x16x32_f16(axq[ks], bx, Dacc, 0, 0, 0);
            }
#pragma unroll
            for (int ks = 0; ks < 2; ++ks) {
                f16x8 bk0 = *reinterpret_cast<const f16x8*>(&k_lds[0][c * 16 + lr][ks * 32 + lg * 8]);
                S0 = __builtin_amdgcn_mfma_f32_16x16x32_f16(aq[0][ks], bk0, S0, 0, 0, 0);
                f16x8 bk1 = *reinterpret_cast<const f16x8*>(&k_lds[1][c * 16 + lr][ks * 32 + lg * 8]);
                S1 = __builtin_amdgcn_mfma_f32_16x16x32_f16(aq[1][ks], bk1, S1, 0, 0, 0);
            }
            float sqj = sq_lds[c * 16 + lr];
            float sp[4];
#pragma unroll
            for (int r = 0; r < 4; ++r) sp[r] = spa_t[rowoff[r] + c * 16];
#pragma unroll
            for (int r = 0; r < 4; ++r) {
                float d2 = fmaf(-2.f, Dacc[r], sqi[r] + sqj);
                float sd = fsqrt_raw(fmaxf(d2, 0.f));
                float spe = fexp2_raw(sd * nc1L);
                float mskL = sp[r] * spe;
                float p0 = fexp2_raw(fmaf(S0[r], mskL, NEG8L));
                float p1 = fexp2_raw(fmaf(S1[r], mskL, NEG8L));
                lsum[0][r] += p0;
                lsum[1][r] += p1;
                p_lds[w][0][lg * 4 + r][c * 16 + lr] = f2h(p0);
                p_lds[w][1][lg * 4 + r][c * 16 + lr] = f2h(p1);
            }
        }
#pragma unroll
        for (int h = 0; h < 2; ++h) {
            f16x8 pa = *reinterpret_cast<const f16x8*>(&p_lds[w][h][lr][lg * 8]);
#pragma unroll
            for (int vd = 0; vd < 4; ++vd) {
                f16x8 bv = *reinterpret_cast<const f16x8*>(&vt_lds[h][vd * 16 + lr][lg * 8]);
                O[h][vd] = __builtin_amdgcn_mfma_f32_16x16x32_f16(pa, bv, O[h][vd], 0, 0, 0);
            }
        }
    }
    // ---- epilogue ----
#pragma unroll
    for (int r = 0; r < 4; ++r) {
        int q = q0 + lg * 4 + r;
#pragma unroll
        for (int h = 0; h < 2; ++h) {
            float ls = lsum[h][r];
#pragma unroll
            for (int m = 1; m < 16; m <<= 1) ls += __shfl_xor(ls, m, 64);
            size_t base = (((size_t)split * 2 + b) * 2 + h) * 4096 + q;
            if (lr == 0) l_ws[base] = ls;
#pragma unroll
            for (int vd = 0; vd < 4; ++vd)
                opart[base * 64 + vd * 16 + lr] = f2h(O[h][vd][r]);
        }
    }
}

// ---------------- ff1 with fused split-combine: (sum_s opart / sum_s l) @ W1 + gelu ----------------
__global__ __launch_bounds__(256) void ff1_comb(const u16* __restrict__ opart,
                                                const float* __restrict__ l_ws,
                                                const u16* __restrict__ w1,
                                                const float* __restrict__ bias,
                                                u16* __restrict__ h1) {
    int cg = blockIdx.x & 1;
    int tok0 = (blockIdx.x >> 1) * 64 + (threadIdx.x >> 6) * 16;
    int lane = threadIdx.x & 63, lr = lane & 15, lg = lane >> 4;
    int tok = tok0 + lr;
    int b = tok >> 12, n = tok & 4095;
    float rL[2];
#pragma unroll
    for (int h = 0; h < 2; ++h) {
        float L = 0.f;
#pragma unroll
        for (int s = 0; s < 8; ++s)
            L += l_ws[(((size_t)s * 2 + b) * 2 + h) * 4096 + n];
        rL[h] = frcp_raw(L);
    }
    f16x8 a[4];
#pragma unroll
    for (int ks = 0; ks < 4; ++ks) {
        int d0 = ks * 32 + lg * 8;
        int h = d0 >> 6, dh = d0 & 63;
        float o8[8] = {0.f, 0.f, 0.f, 0.f, 0.f, 0.f, 0.f, 0.f};
#pragma unroll
        for (int s = 0; s < 8; ++s) {
            f16x8 ov = *reinterpret_cast<const f16x8*>(
                opart + ((((size_t)s * 2 + b) * 2 + h) * 4096 + n) * 64 + dh);
#pragma unroll
            for (int e = 0; e < 8; ++e) o8[e] += (float)ov[e];
        }
        f16x8 av;
#pragma unroll
        for (int e = 0; e < 8; ++e) av[e] = (_Float16)(o8[e] * rL[h]);
        a[ks] = av;
    }
#pragma unroll
    for (int ci = 0; ci < 4; ++ci) {
        int c = cg * 4 + ci;
        f32x4 acc = {0.f, 0.f, 0.f, 0.f};
#pragma unroll
        for (int ks = 0; ks < 4; ++ks) {
            f16x8 bw = *reinterpret_cast<const f16x8*>(w1 + (size_t)(c * 16 + lr) * 128 + ks * 32 + lg * 8);
            acc = __builtin_amdgcn_mfma_f32_16x16x32_f16(a[ks], bw, acc, 0, 0, 0);
        }
        int j = c * 16 + lr;
        float bv = bias[j];
#pragma unroll
        for (int r = 0; r < 4; ++r) {
            int tk = tok0 + lg * 4 + r;
            float val = acc[r] + bv;
            float g = 0.5f * val * (1.f + erff(val * 0.7071067811865475f));
            h1[(size_t)tk * 128 + j] = f2h(g);
        }
    }
}

// ---------------- ff2: [8192,128]@[128,128] -> f32 out ----------------
__global__ __launch_bounds__(256) void ff2_gemm(const u16* __restrict__ in, const u16* __restrict__ w,
                                                const float* __restrict__ bias, float* __restrict__ out) {
    int cg = blockIdx.x & 1;
    int tok0 = (blockIdx.x >> 1) * 64 + (threadIdx.x >> 6) * 16;
    int lane = threadIdx.x & 63, lr = lane & 15, lg = lane >> 4;
    f16x8 a[4];
#pragma unroll
    for (int ks = 0; ks < 4; ++ks)
        a[ks] = *reinterpret_cast<const f16x8*>(in + (size_t)(tok0 + lr) * 128 + ks * 32 + lg * 8);
#pragma unroll
    for (int ci = 0; ci < 4; ++ci) {
        int c = cg * 4 + ci;
        f32x4 acc = {0.f, 0.f, 0.f, 0.f};
#pragma unroll
        for (int ks = 0; ks < 4; ++ks) {
            f16x8 bw = *reinterpret_cast<const f16x8*>(w + (size_t)(c * 16 + lr) * 128 + ks * 32 + lg * 8);
            acc = __builtin_amdgcn_mfma_f32_16x16x32_f16(a[ks], bw, acc, 0, 0, 0);
        }
        int j = c * 16 + lr;
        float bv = bias[j];
#pragma unroll
        for (int r = 0; r < 4; ++r) {
            int tok = tok0 + lg * 4 + r;
            out[(size_t)tok * 128 + j] = acc[r] + bv;
        }
    }
}

extern "C" void kernel_launch(void* const* d_in, const int* in_sizes, int n_in,
                              void* d_out, int out_size, void* d_ws, size_t ws_size,
                              hipStream_t stream) {
    const float* x     = (const float*)d_in[0];
    const float* v_qkv = (const float*)d_in[1];
    const float* g_qkv = (const float*)d_in[2];
    const float* b_qkv = (const float*)d_in[3];
    const float* v_ff1 = (const float*)d_in[4];
    const float* g_ff1 = (const float*)d_in[5];
    const float* b_ff1 = (const float*)d_in[6];
    const float* v_ff2 = (const float*)d_in[7];
    const float* g_ff2 = (const float*)d_in[8];
    const float* b_ff2 = (const float*)d_in[9];

    char* w = (char*)d_ws;
    size_t off = 0;
    float* accum   = (float*)(w + off); off += 256;
    float* partial = (float*)(w + off); off += 1056 * 4 + 128;
    float* spa_tab = (float*)(w + off); off += (size_t)127 * 4096 * 4;
    u16* xh      = (u16*)(w + off);   off += (size_t)8192 * 128 * 2;
    float* sqv   = (float*)(w + off); off += (size_t)8192 * 4;
    u16* wqkv    = (u16*)(w + off);   off += (size_t)384 * 128 * 2;
    u16* w1      = (u16*)(w + off);   off += (size_t)128 * 128 * 2;
    u16* w2      = (u16*)(w + off);   off += (size_t)128 * 128 * 2;
    u16* q_ws    = (u16*)(w + off);   off += (size_t)4 * 4096 * 64 * 2;
    u16* k_ws    = (u16*)(w + off);   off += (size_t)4 * 4096 * 64 * 2;
    u16* vt_ws   = (u16*)(w + off);   off += (size_t)4 * 4096 * 64 * 2;
    u16* opart   = (u16*)(w + off);   off += (size_t)32 * 4096 * 64 * 2;
    float* l_ws  = (float*)(w + off); off += (size_t)32 * 4096 * 4;
    u16* h1      = (u16*)(w + off);   off += (size_t)8192 * 128 * 2;

    // sigma_spa: exact closed form over grid-delta histogram
    double ssum = 0.0;
    for (int dx = -63; dx <= 63; ++dx) {
        int adx = dx < 0 ? -dx : dx;
        for (int dy = -63; dy <= 63; ++dy) {
            int ady = dy < 0 ? -dy : dy;
            ssum += (double)(64 - adx) * (double)(64 - ady) * sqrt((double)(dx * dx + dy * dy));
        }
    }
    float sigma_spa = (float)(ssum / (4096.0 * 4096.0));
    float c2 = 1.0f / (2.0f * sigma_spa * sigma_spa);

    hipMemsetAsync(w, 0, 256 + 1056 * 4 + 128, stream);  // accum + sigma partials

    prep_all<<<4240, 256, 0, stream>>>(x, xh, sqv, v_qkv, g_qkv, v_ff1, g_ff1,
                                       v_ff2, g_ff2, wqkv, w1, w2, spa_tab, c2);
    sigma_gemm<<<1056, 256, 0, stream>>>(xh, sqv, partial);
    sigma_fin<<<1, 256, 0, stream>>>(partial, accum);
    qkv_gemm<<<256, 256, 0, stream>>>(xh, wqkv, b_qkv, q_ws, k_ws, vt_ws);
    attn_fused<<<1024, 256, 0, stream>>>(xh, sqv, q_ws, k_ws, vt_ws, accum, spa_tab, opart, l_ws);
    ff1_comb<<<256, 256, 0, stream>>>(opart, l_ws, w1, b_ff1, h1);
    ff2_gemm<<<256, 256, 0, stream>>>(h1, w2, b_ff2, (float*)d_out);
}

// Round 7
// 204.591 us; speedup vs baseline: 1.4821x; 1.4821x over previous
//
#include <hip/hip_runtime.h>
#include <hip/hip_fp16.h>
#include <math.h>

typedef unsigned short u16;
typedef _Float16 f16x8 __attribute__((ext_vector_type(8)));
typedef float f32x4 __attribute__((ext_vector_type(4)));

#define LOG2E 1.4426950408889634f

static __device__ __forceinline__ u16 f2h(float f) {
    _Float16 h = (_Float16)f;
    return __builtin_bit_cast(u16, h);
}
// raw v_sqrt/v_exp/v_rcp (~1ULP) — avoid IEEE guarded expansions
static __device__ __forceinline__ float fsqrt_raw(float x) {
    float r; asm("v_sqrt_f32 %0, %1" : "=v"(r) : "v"(x)); return r;
}
static __device__ __forceinline__ float fexp2_raw(float x) {
    float r; asm("v_exp_f32 %0, %1" : "=v"(r) : "v"(x)); return r;
}
static __device__ __forceinline__ float frcp_raw(float x) {
    float r; asm("v_rcp_f32 %0, %1" : "=v"(r) : "v"(x)); return r;
}
// async global->LDS, 16B per lane; LDS dest = wave-uniform base + lane*16
static __device__ __forceinline__ void gload16(const void* g, void* l) {
    __builtin_amdgcn_global_load_lds(
        (const __attribute__((address_space(1))) void*)g,
        (__attribute__((address_space(3))) void*)l, 16, 0, 0);
}

// ---------------- fused prep: x->f16+sq | weight-norm | spa table | zero ctrl ----------------
__global__ __launch_bounds__(256) void prep_all(
    const float* __restrict__ x, u16* __restrict__ xh, float* __restrict__ sq,
    const float* __restrict__ vq, const float* __restrict__ gq,
    const float* __restrict__ v1, const float* __restrict__ g1,
    const float* __restrict__ v2, const float* __restrict__ g2,
    u16* __restrict__ wq, u16* __restrict__ w1, u16* __restrict__ w2,
    float* __restrict__ tab, float c2,
    float* __restrict__ accum, float* __restrict__ partial) {
    int bid = blockIdx.x, tid = threadIdx.x;
    int wave = tid >> 6, lane = tid & 63;
    if (bid < 2048) {
        int row = bid * 4 + wave;
        const float2 v = *reinterpret_cast<const float2*>(x + (size_t)row * 128 + lane * 2);
        float ss = v.x * v.x + v.y * v.y;
#pragma unroll
        for (int m = 1; m < 64; m <<= 1) ss += __shfl_xor(ss, m, 64);
        unsigned int packed = (unsigned int)f2h(v.x) | ((unsigned int)f2h(v.y) << 16);
        *reinterpret_cast<unsigned int*>(xh + (size_t)row * 128 + lane * 2) = packed;
        if (lane == 0) sq[row] = ss;
    } else if (bid < 2208) {
        int row = (bid - 2048) * 4 + wave;
        const float* src; float gv; u16* dst; int r;
        if (row < 384)      { r = row;       src = vq + (size_t)r * 128; gv = gq[r]; dst = wq + (size_t)r * 128; }
        else if (row < 512) { r = row - 384; src = v1 + (size_t)r * 128; gv = g1[r]; dst = w1 + (size_t)r * 128; }
        else                { r = row - 512; src = v2 + (size_t)r * 128; gv = g2[r]; dst = w2 + (size_t)r * 128; }
        float2 v = *reinterpret_cast<const float2*>(src + lane * 2);
        float ss = v.x * v.x + v.y * v.y;
#pragma unroll
        for (int m = 1; m < 64; m <<= 1) ss += __shfl_xor(ss, m, 64);
        float sc = gv / sqrtf(ss);
        unsigned int packed = (unsigned int)f2h(v.x * sc) | ((unsigned int)f2h(v.y * sc) << 16);
        *reinterpret_cast<unsigned int*>(dst + lane * 2) = packed;
    } else if (bid < 4240) {
        int id = (bid - 2208) * 256 + tid;
        int dxi = id >> 12, rem = id & 4095;
        int iy = rem >> 6, jy = rem & 63;
        float dx = (float)(dxi - 63), dy = (float)(iy - jy);
        float d = fsqrt_raw(fmaf(dx, dx, dy * dy));
        tab[id] = LOG2E * fexp2_raw(-d * c2 * LOG2E);
    } else {
        // zero control region (ticket etc.) + sigma partials
        for (int i = tid; i < 1056; i += 256) partial[i] = 0.f;
        if (tid < 16) accum[tid] = 0.f;
    }
}

// ---------------- mid: sigma (symmetric tiles + last-block fin) | qkv projection ----------------
__global__ __launch_bounds__(256) void mid_fused(
    const u16* __restrict__ xh, const float* __restrict__ sq,
    float* __restrict__ partial, float* __restrict__ accum, unsigned int* __restrict__ ticket,
    const u16* __restrict__ wqkv, const float* __restrict__ bq,
    u16* __restrict__ q_ws, u16* __restrict__ k_ws, u16* __restrict__ vt_ws) {
    __shared__ u16 xi[128][136];
    __shared__ u16 xj[128][136];
    __shared__ float red[4];
    __shared__ int is_last;
    int bid = blockIdx.x, tid = threadIdx.x;
    int wv = tid >> 6, lane = tid & 63, lr = lane & 15, lg = lane >> 4;
    if (bid < 1056) {
        // ---- sigma_spe over ti<=tj tiles ----
        int b = bid >= 528;
        int idx = bid - b * 528;
        int ti = 0;
        while (idx >= 32 - ti) { idx -= 32 - ti; ++ti; }
        int tj = ti + idx;
        int i0 = ti * 128, j0 = tj * 128;
        float wgt = (ti == tj) ? 1.f : 2.f;
        const u16* xsrc = xh + (size_t)b * 4096 * 128;
        for (int t = tid; t < 2048; t += 256) {
            int row = t >> 4, c = (t & 15) * 8;
            *reinterpret_cast<uint4*>(&xi[row][c]) =
                *reinterpret_cast<const uint4*>(xsrc + (size_t)(i0 + row) * 128 + c);
        }
        for (int t = tid; t < 2048; t += 256) {
            int row = t >> 4, c = (t & 15) * 8;
            *reinterpret_cast<uint4*>(&xj[row][c]) =
                *reinterpret_cast<const uint4*>(xsrc + (size_t)(j0 + row) * 128 + c);
        }
        __syncthreads();
        f16x8 ai[2][4];
#pragma unroll
        for (int m2 = 0; m2 < 2; ++m2)
#pragma unroll
            for (int ks = 0; ks < 4; ++ks)
                ai[m2][ks] = *reinterpret_cast<const f16x8*>(&xi[wv * 32 + m2 * 16 + lr][ks * 32 + lg * 8]);
        const float* sqb = sq + (size_t)b * 4096;
        float sqi[2][4];
#pragma unroll
        for (int m2 = 0; m2 < 2; ++m2)
#pragma unroll
            for (int r = 0; r < 4; ++r)
                sqi[m2][r] = sqb[i0 + wv * 32 + m2 * 16 + lg * 4 + r];
        float lsum = 0.f;
        const f32x4 zero4 = {0.f, 0.f, 0.f, 0.f};
#pragma unroll
        for (int c = 0; c < 8; ++c) {
            f16x8 bj[4];
#pragma unroll
            for (int ks = 0; ks < 4; ++ks)
                bj[ks] = *reinterpret_cast<const f16x8*>(&xj[c * 16 + lr][ks * 32 + lg * 8]);
            float sqj = sqb[j0 + c * 16 + lr];
#pragma unroll
            for (int m2 = 0; m2 < 2; ++m2) {
                f32x4 acc = zero4;
#pragma unroll
                for (int ks = 0; ks < 4; ++ks)
                    acc = __builtin_amdgcn_mfma_f32_16x16x32_f16(ai[m2][ks], bj[ks], acc, 0, 0, 0);
#pragma unroll
                for (int r = 0; r < 4; ++r) {
                    float d2 = fmaf(-2.f, acc[r], sqi[m2][r] + sqj);
                    lsum += fsqrt_raw(fmaxf(d2, 0.f));
                }
            }
        }
#pragma unroll
        for (int m = 1; m < 64; m <<= 1) lsum += __shfl_xor(lsum, m, 64);
        if (lane == 0) red[wv] = lsum;
        __syncthreads();
        if (tid == 0) {
            partial[bid] = (red[0] + red[1] + red[2] + red[3]) * wgt;
            __threadfence();
            unsigned int old = atomicAdd(ticket, 1u);
            is_last = (old == 1055u);
        }
        __syncthreads();
        if (is_last) {
            float s = 0.f;
            for (int i = tid; i < 1056; i += 256) s += partial[i];
#pragma unroll
            for (int m = 1; m < 64; m <<= 1) s += __shfl_xor(s, m, 64);
            if (lane == 0) red[wv] = s;
            __syncthreads();
            if (tid == 0) {
                float sigma = (red[0] + red[1] + red[2] + red[3]) / 33554432.f;  // 2*4096*4096
                accum[1] = -LOG2E / (2.f * sigma * sigma);  // -c1*log2(e)
            }
        }
    } else {
        // ---- qkv projection (q pre-scaled by 1/8) ----
        int qb = bid - 1056;
        int cg = qb & 1;
        int tok0 = (qb >> 1) * 64 + wv * 16;
        f16x8 a[4];
#pragma unroll
        for (int ks = 0; ks < 4; ++ks)
            a[ks] = *reinterpret_cast<const f16x8*>(xh + (size_t)(tok0 + lr) * 128 + ks * 32 + lg * 8);
#pragma unroll
        for (int ci = 0; ci < 12; ++ci) {
            int c = cg * 12 + ci;
            f32x4 acc = {0.f, 0.f, 0.f, 0.f};
#pragma unroll
            for (int ks = 0; ks < 4; ++ks) {
                f16x8 bw = *reinterpret_cast<const f16x8*>(wqkv + (size_t)(c * 16 + lr) * 128 + ks * 32 + lg * 8);
                acc = __builtin_amdgcn_mfma_f32_16x16x32_f16(a[ks], bw, acc, 0, 0, 0);
            }
            int j = c * 16 + lr;
            float bias = bq[j];
            float sc = (j < 128) ? 0.125f : 1.0f;
#pragma unroll
            for (int r = 0; r < 4; ++r) {
                int tokg = tok0 + lg * 4 + r;
                int b = tokg >> 12, n = tokg & 4095;
                u16 hv = f2h((acc[r] + bias) * sc);
                if (j < 128) {
                    q_ws[((size_t)(b * 2 + (j >> 6)) * 4096 + n) * 64 + (j & 63)] = hv;
                } else if (j < 256) {
                    int jj = j - 128;
                    k_ws[((size_t)(b * 2 + (jj >> 6)) * 4096 + n) * 64 + (jj & 63)] = hv;
                } else {
                    int jj = j - 256;
                    vt_ws[((size_t)(b * 2 + (jj >> 6)) * 64 + (jj & 63)) * 4096 + n] = hv;
                }
            }
        }
    }
}

// ---------------- fused masked attention: gload_lds double-buffer, 2-phase pipeline ----------------
__global__ __launch_bounds__(256, 2) void attn_fused(
    const u16* __restrict__ xh, const float* __restrict__ sq,
    const u16* __restrict__ q_ws, const u16* __restrict__ k_ws, const u16* __restrict__ vt_ws,
    const float* __restrict__ accum, const float* __restrict__ spa,
    u16* __restrict__ opart, float* __restrict__ l_ws) {
    // dbuf tiles (linear, XOR-swizzled both sides): per buf 4096 u16 each
    __shared__ u16 k_lds[2][4096];       // [h][key32][dh64], 128B rows, swz ((row&7)<<4)
    __shared__ u16 vt_lds[2][4096];      // [h][dh64][key32],  64B rows, swz (((row>>1)&3)<<4)
    __shared__ u16 xk_lds[2][4096];      // [key32][d128],    256B rows, swz ((row&7)<<4)
    __shared__ u16 p_lds[4][2][16][40];  // wave-private P
    // total 59392 B -> 2 blocks/CU

    const float nc1L = accum[1];
    const float NEG8L = -8.0f * LOG2E;
    int idx = blockIdx.x;                        // 1024 blocks
    int qt = idx & 63, split = (idx >> 6) & 7, b = idx >> 9;
    int tid = threadIdx.x;
    int w = tid >> 6, lane = tid & 63, lr = lane & 15, lg = lane >> 4;
    int q0 = qt * 64 + w * 16;
    int kb0 = split * 512;

    f16x8 aq[2][2], axq[4];
#pragma unroll
    for (int h = 0; h < 2; ++h)
#pragma unroll
        for (int ks = 0; ks < 2; ++ks)
            aq[h][ks] = *reinterpret_cast<const f16x8*>(
                q_ws + ((size_t)(b * 2 + h) * 4096 + q0 + lr) * 64 + ks * 32 + lg * 8);
#pragma unroll
    for (int ks = 0; ks < 4; ++ks)
        axq[ks] = *reinterpret_cast<const f16x8*>(
            xh + ((size_t)b * 4096 + q0 + lr) * 128 + ks * 32 + lg * 8);

    float sqi[4];
    int rowoff[4];
#pragma unroll
    for (int r = 0; r < 4; ++r) {
        sqi[r] = sq[(size_t)b * 4096 + q0 + lg * 4 + r];
        rowoff[r] = (w * 16 + lg * 4 + r) * 64 + lr;
    }

    // ---- per-lane staging addresses (pre-swizzled global sources) ----
    const char* kgp[2]; const char* vgp[2]; const char* xgp[2];
    int klo[2], vlo[2], xlo[2];   // wave-uniform LDS byte offsets
#pragma unroll
    for (int j = 0; j < 2; ++j) {
        int i = w * 2 + j;                       // 8 wave-instrs per tile-array
        int off = i * 1024 + lane * 16;          // [0,8192)
        {   // K: per-head 4096B, row stride 128B (global == LDS stride)
            int h = off >> 12, offh = off & 4095;
            int raw = offh ^ ((offh >> 3) & 0x70);           // XOR bits[6:4] ^= row&7
            kgp[j] = (const char*)k_ws + (((size_t)(b * 2 + h) * 4096 + kb0) * 128) + raw;
        }
        {   // V^T: per-head 4096B, LDS row=dh stride 64B, global row stride 8192B
            int h = off >> 12, offh = off & 4095;
            int row = offh >> 6, col = offh & 63;
            int colp = col ^ ((row & 6) << 3);               // XOR bits[5:4] ^= (row>>1)&3
            vgp[j] = (const char*)vt_ws + ((((size_t)(b * 2 + h) * 64 + row) * 4096 + kb0) * 2) + colp;
        }
        {   // X_k: 8192B, row stride 256B (global == LDS stride)
            int raw = off ^ ((off >> 4) & 0x70);             // XOR bits[6:4] ^= row&7
            xgp[j] = (const char*)xh + ((size_t)b * 4096 + kb0) * 256 + raw;
        }
        klo[j] = i * 1024; vlo[j] = i * 1024; xlo[j] = i * 1024;
    }

    const f32x4 zero4 = {0.f, 0.f, 0.f, 0.f};
    f32x4 O[2][4];
    float lsum[2][4];
#pragma unroll
    for (int h = 0; h < 2; ++h)
#pragma unroll
        for (int vd = 0; vd < 4; ++vd) O[h][vd] = zero4;
#pragma unroll
    for (int h = 0; h < 2; ++h)
#pragma unroll
        for (int r = 0; r < 4; ++r) lsum[h][r] = 0.f;

    auto stage = [&](int buf) {
        int bo = buf * 8192;
#pragma unroll
        for (int j = 0; j < 2; ++j) {
            gload16(kgp[j], (char*)k_lds + bo + klo[j]);
            gload16(vgp[j], (char*)vt_lds + bo + vlo[j]);
            gload16(xgp[j], (char*)xk_lds + bo + xlo[j]);
        }
    };
    auto advance = [&]() {
#pragma unroll
        for (int j = 0; j < 2; ++j) { kgp[j] += 4096; vgp[j] += 64; xgp[j] += 8192; }
    };

    stage(0);
    advance();
    asm volatile("s_waitcnt vmcnt(0)" ::: "memory");
    __syncthreads();

    int cur = 0;
    int sx = (lr & 7) << 3;                      // u16-index XOR for K/X reads
    int sv = ((lr >> 1) & 3) << 3;               // u16-index XOR for V reads
    for (int t = 0; t < 16; ++t) {
        if (t < 15) { stage(cur ^ 1); advance(); }   // issue next tile, no wait

        int kb = kb0 + t * 32;
        int dxi = qt - (kb >> 6) + 63;
        const float* spa_t = spa + (size_t)dxi * 4096 + (kb & 63);
#pragma unroll
        for (int c = 0; c < 2; ++c) {
            int row = c * 16 + lr;
            f32x4 Dacc = zero4, S0 = zero4, S1 = zero4;
#pragma unroll
            for (int ks = 0; ks < 4; ++ks) {
                f16x8 bx = *reinterpret_cast<const f16x8*>(&xk_lds[cur][row * 128 + ((ks * 32 + lg * 8) ^ sx)]);
                Dacc = __builtin_amdgcn_mfma_f32_16x16x32_f16(axq[ks], bx, Dacc, 0, 0, 0);
            }
#pragma unroll
            for (int ks = 0; ks < 2; ++ks) {
                f16x8 bk0 = *reinterpret_cast<const f16x8*>(&k_lds[cur][row * 64 + ((ks * 32 + lg * 8) ^ sx)]);
                S0 = __builtin_amdgcn_mfma_f32_16x16x32_f16(aq[0][ks], bk0, S0, 0, 0, 0);
                f16x8 bk1 = *reinterpret_cast<const f16x8*>(&k_lds[cur][2048 + row * 64 + ((ks * 32 + lg * 8) ^ sx)]);
                S1 = __builtin_amdgcn_mfma_f32_16x16x32_f16(aq[1][ks], bk1, S1, 0, 0, 0);
            }
            float sqj = sq[(size_t)b * 4096 + kb + row];     // L2-hot
            float sp[4];
#pragma unroll
            for (int r = 0; r < 4; ++r) sp[r] = spa_t[rowoff[r] + c * 16];
#pragma unroll
            for (int r = 0; r < 4; ++r) {
                float d2 = fmaf(-2.f, Dacc[r], sqi[r] + sqj);
                float sd = fsqrt_raw(fmaxf(d2, 0.f));
                float spe = fexp2_raw(sd * nc1L);
                float mskL = sp[r] * spe;
                float p0 = fexp2_raw(fmaf(S0[r], mskL, NEG8L));
                float p1 = fexp2_raw(fmaf(S1[r], mskL, NEG8L));
                lsum[0][r] += p0;
                lsum[1][r] += p1;
                p_lds[w][0][lg * 4 + r][c * 16 + lr] = f2h(p0);
                p_lds[w][1][lg * 4 + r][c * 16 + lr] = f2h(p1);
            }
        }
#pragma unroll
        for (int h = 0; h < 2; ++h) {
            f16x8 pa = *reinterpret_cast<const f16x8*>(&p_lds[w][h][lr][lg * 8]);
#pragma unroll
            for (int vd = 0; vd < 4; ++vd) {
                f16x8 bv = *reinterpret_cast<const f16x8*>(
                    &vt_lds[cur][h * 2048 + (vd * 16 + lr) * 32 + ((lg * 8) ^ sv)]);
                O[h][vd] = __builtin_amdgcn_mfma_f32_16x16x32_f16(pa, bv, O[h][vd], 0, 0, 0);
            }
        }
        asm volatile("s_waitcnt vmcnt(0)" ::: "memory");   // next tile landed
        __syncthreads();
        cur ^= 1;
    }
    // ---- epilogue: unnormalized O (f16) + row-sums l ----
#pragma unroll
    for (int r = 0; r < 4; ++r) {
        int q = q0 + lg * 4 + r;
#pragma unroll
        for (int h = 0; h < 2; ++h) {
            float ls = lsum[h][r];
#pragma unroll
            for (int m = 1; m < 16; m <<= 1) ls += __shfl_xor(ls, m, 64);
            size_t base = (((size_t)split * 2 + b) * 2 + h) * 4096 + q;
            if (lr == 0) l_ws[base] = ls;
#pragma unroll
            for (int vd = 0; vd < 4; ++vd)
                opart[base * 64 + vd * 16 + lr] = f2h(O[h][vd][r]);
        }
    }
}

// ---------------- ff1 with fused split-combine: (sum_s opart / sum_s l) @ W1 + gelu ----------------
__global__ __launch_bounds__(256) void ff1_comb(const u16* __restrict__ opart,
                                                const float* __restrict__ l_ws,
                                                const u16* __restrict__ w1,
                                                const float* __restrict__ bias,
                                                u16* __restrict__ h1) {
    int cg = blockIdx.x & 1;
    int tok0 = (blockIdx.x >> 1) * 64 + (threadIdx.x >> 6) * 16;
    int lane = threadIdx.x & 63, lr = lane & 15, lg = lane >> 4;
    int tok = tok0 + lr;
    int b = tok >> 12, n = tok & 4095;
    float rL[2];
#pragma unroll
    for (int h = 0; h < 2; ++h) {
        float L = 0.f;
#pragma unroll
        for (int s = 0; s < 8; ++s)
            L += l_ws[(((size_t)s * 2 + b) * 2 + h) * 4096 + n];
        rL[h] = frcp_raw(L);
    }
    f16x8 a[4];
#pragma unroll
    for (int ks = 0; ks < 4; ++ks) {
        int d0 = ks * 32 + lg * 8;
        int h = d0 >> 6, dh = d0 & 63;
        float o8[8] = {0.f, 0.f, 0.f, 0.f, 0.f, 0.f, 0.f, 0.f};
#pragma unroll
        for (int s = 0; s < 8; ++s) {
            f16x8 ov = *reinterpret_cast<const f16x8*>(
                opart + ((((size_t)s * 2 + b) * 2 + h) * 4096 + n) * 64 + dh);
#pragma unroll
            for (int e = 0; e < 8; ++e) o8[e] += (float)ov[e];
        }
        f16x8 av;
#pragma unroll
        for (int e = 0; e < 8; ++e) av[e] = (_Float16)(o8[e] * rL[h]);
        a[ks] = av;
    }
#pragma unroll
    for (int ci = 0; ci < 4; ++ci) {
        int c = cg * 4 + ci;
        f32x4 acc = {0.f, 0.f, 0.f, 0.f};
#pragma unroll
        for (int ks = 0; ks < 4; ++ks) {
            f16x8 bw = *reinterpret_cast<const f16x8*>(w1 + (size_t)(c * 16 + lr) * 128 + ks * 32 + lg * 8);
            acc = __builtin_amdgcn_mfma_f32_16x16x32_f16(a[ks], bw, acc, 0, 0, 0);
        }
        int j = c * 16 + lr;
        float bv = bias[j];
#pragma unroll
        for (int r = 0; r < 4; ++r) {
            int tk = tok0 + lg * 4 + r;
            float val = acc[r] + bv;
            float g = 0.5f * val * (1.f + erff(val * 0.7071067811865475f));
            h1[(size_t)tk * 128 + j] = f2h(g);
        }
    }
}

// ---------------- ff2: [8192,128]@[128,128] -> f32 out ----------------
__global__ __launch_bounds__(256) void ff2_gemm(const u16* __restrict__ in, const u16* __restrict__ w,
                                                const float* __restrict__ bias, float* __restrict__ out) {
    int cg = blockIdx.x & 1;
    int tok0 = (blockIdx.x >> 1) * 64 + (threadIdx.x >> 6) * 16;
    int lane = threadIdx.x & 63, lr = lane & 15, lg = lane >> 4;
    f16x8 a[4];
#pragma unroll
    for (int ks = 0; ks < 4; ++ks)
        a[ks] = *reinterpret_cast<const f16x8*>(in + (size_t)(tok0 + lr) * 128 + ks * 32 + lg * 8);
#pragma unroll
    for (int ci = 0; ci < 4; ++ci) {
        int c = cg * 4 + ci;
        f32x4 acc = {0.f, 0.f, 0.f, 0.f};
#pragma unroll
        for (int ks = 0; ks < 4; ++ks) {
            f16x8 bw = *reinterpret_cast<const f16x8*>(w + (size_t)(c * 16 + lr) * 128 + ks * 32 + lg * 8);
            acc = __builtin_amdgcn_mfma_f32_16x16x32_f16(a[ks], bw, acc, 0, 0, 0);
        }
        int j = c * 16 + lr;
        float bv = bias[j];
#pragma unroll
        for (int r = 0; r < 4; ++r) {
            int tok = tok0 + lg * 4 + r;
            out[(size_t)tok * 128 + j] = acc[r] + bv;
        }
    }
}

extern "C" void kernel_launch(void* const* d_in, const int* in_sizes, int n_in,
                              void* d_out, int out_size, void* d_ws, size_t ws_size,
                              hipStream_t stream) {
    const float* x     = (const float*)d_in[0];
    const float* v_qkv = (const float*)d_in[1];
    const float* g_qkv = (const float*)d_in[2];
    const float* b_qkv = (const float*)d_in[3];
    const float* v_ff1 = (const float*)d_in[4];
    const float* g_ff1 = (const float*)d_in[5];
    const float* b_ff1 = (const float*)d_in[6];
    const float* v_ff2 = (const float*)d_in[7];
    const float* g_ff2 = (const float*)d_in[8];
    const float* b_ff2 = (const float*)d_in[9];

    char* w = (char*)d_ws;
    size_t off = 0;
    float* accum   = (float*)(w + off); off += 256;
    float* partial = (float*)(w + off); off += 1056 * 4 + 128;
    float* spa_tab = (float*)(w + off); off += (size_t)127 * 4096 * 4;
    u16* xh      = (u16*)(w + off);   off += (size_t)8192 * 128 * 2;
    float* sqv   = (float*)(w + off); off += (size_t)8192 * 4;
    u16* wqkv    = (u16*)(w + off);   off += (size_t)384 * 128 * 2;
    u16* w1      = (u16*)(w + off);   off += (size_t)128 * 128 * 2;
    u16* w2      = (u16*)(w + off);   off += (size_t)128 * 128 * 2;
    u16* q_ws    = (u16*)(w + off);   off += (size_t)4 * 4096 * 64 * 2;
    u16* k_ws    = (u16*)(w + off);   off += (size_t)4 * 4096 * 64 * 2;
    u16* vt_ws   = (u16*)(w + off);   off += (size_t)4 * 4096 * 64 * 2;
    u16* opart   = (u16*)(w + off);   off += (size_t)32 * 4096 * 64 * 2;
    float* l_ws  = (float*)(w + off); off += (size_t)32 * 4096 * 4;
    u16* h1      = (u16*)(w + off);   off += (size_t)8192 * 128 * 2;
    unsigned int* ticket = (unsigned int*)accum + 4;

    // sigma_spa: exact closed form over grid-delta histogram
    double ssum = 0.0;
    for (int dx = -63; dx <= 63; ++dx) {
        int adx = dx < 0 ? -dx : dx;
        for (int dy = -63; dy <= 63; ++dy) {
            int ady = dy < 0 ? -dy : dy;
            ssum += (double)(64 - adx) * (double)(64 - ady) * sqrt((double)(dx * dx + dy * dy));
        }
    }
    float sigma_spa = (float)(ssum / (4096.0 * 4096.0));
    float c2 = 1.0f / (2.0f * sigma_spa * sigma_spa);

    prep_all<<<4241, 256, 0, stream>>>(x, xh, sqv, v_qkv, g_qkv, v_ff1, g_ff1,
                                       v_ff2, g_ff2, wqkv, w1, w2, spa_tab, c2,
                                       accum, partial);
    mid_fused<<<1312, 256, 0, stream>>>(xh, sqv, partial, accum, ticket,
                                        wqkv, b_qkv, q_ws, k_ws, vt_ws);
    attn_fused<<<1024, 256, 0, stream>>>(xh, sqv, q_ws, k_ws, vt_ws, accum, spa_tab, opart, l_ws);
    ff1_comb<<<256, 256, 0, stream>>>(opart, l_ws, w1, b_ff1, h1);
    ff2_gemm<<<256, 256, 0, stream>>>(h1, w2, b_ff2, (float*)d_out);
}